// Round 1
// baseline (352.397 us; speedup 1.0000x reference)
//
#include <hip/hip_runtime.h>

typedef short s16x8 __attribute__((ext_vector_type(8)));
typedef float f32x4 __attribute__((ext_vector_type(4)));

#define MFMA16(a, b, c) __builtin_amdgcn_mfma_f32_16x16x32_bf16((a), (b), (c), 0, 0, 0)

__device__ __forceinline__ unsigned short f2bf(float f) {
  unsigned int u = __float_as_uint(f);
  u += 0x7fffu + ((u >> 16) & 1u);
  return (unsigned short)(u >> 16);
}

// ---------------- fp32 -> bf16 convert (x) ----------------
__global__ __launch_bounds__(256) void k_convert_x(const float* __restrict__ x,
                                                   unsigned short* __restrict__ xb) {
  int i = blockIdx.x * 256 + threadIdx.x;  // grid sized exactly: 8192*512/4 threads
  float4 v = ((const float4*)x)[i];
  ushort4 o;
  o.x = f2bf(v.x); o.y = f2bf(v.y); o.z = f2bf(v.z); o.w = f2bf(v.w);
  ((ushort4*)xb)[i] = o;
}

// ---------------- weight transpose+convert: wt[n*512+k] = bf16(w[k*N+n]) ----------------
__global__ __launch_bounds__(256) void k_transpose_w(const float* __restrict__ w,
                                                     unsigned short* __restrict__ wt, int N) {
  int i = blockIdx.x * 256 + threadIdx.x;  // over N*512, exact grid
  int k = i & 511, n = i >> 9;
  wt[i] = f2bf(w[k * N + n]);
}

// ---------------- QKV projection GEMM ----------------
// C[8192,1536] = A(bf16)[8192,512] * Bt(bf16)[1536,512]^T ; scatter into Q/K/V [bh][n][64]
__global__ __launch_bounds__(256) void k_gemm_qkv(
    const unsigned short* __restrict__ A, const unsigned short* __restrict__ Bt,
    unsigned short* __restrict__ Qb, unsigned short* __restrict__ Kb,
    unsigned short* __restrict__ Vb) {
  __shared__ __align__(16) unsigned short As[64 * 40];
  __shared__ __align__(16) unsigned short Bs[64 * 40];
  const int t = threadIdx.x;
  const int bm = blockIdx.x, bn = blockIdx.y;
  const int w = t >> 6, l = t & 63, quad = l >> 4, lr = l & 15;
  const int wm = (w >> 1) * 32, wn = (w & 1) * 32;
  const f32x4 fz = {0.f, 0.f, 0.f, 0.f};
  f32x4 acc[2][2];
  acc[0][0] = fz; acc[0][1] = fz; acc[1][0] = fz; acc[1][1] = fz;
  const int srow = t >> 2, sc = (t & 3) * 8;
  const unsigned short* ag = A + (bm * 64 + srow) * 512 + sc;
  const unsigned short* bg = Bt + (bn * 64 + srow) * 512 + sc;
  for (int kk = 0; kk < 16; ++kk) {
    __syncthreads();
    *(s16x8*)&As[srow * 40 + sc] = *(const s16x8*)(ag + kk * 32);
    *(s16x8*)&Bs[srow * 40 + sc] = *(const s16x8*)(bg + kk * 32);
    __syncthreads();
    s16x8 af[2], bfr[2];
#pragma unroll
    for (int ti = 0; ti < 2; ++ti)
      af[ti] = *(const s16x8*)&As[(wm + ti * 16 + lr) * 40 + quad * 8];
#pragma unroll
    for (int tj = 0; tj < 2; ++tj)
      bfr[tj] = *(const s16x8*)&Bs[(wn + tj * 16 + lr) * 40 + quad * 8];
#pragma unroll
    for (int ti = 0; ti < 2; ++ti)
#pragma unroll
      for (int tj = 0; tj < 2; ++tj)
        acc[ti][tj] = MFMA16(af[ti], bfr[tj], acc[ti][tj]);
  }
#pragma unroll
  for (int ti = 0; ti < 2; ++ti)
#pragma unroll
    for (int tj = 0; tj < 2; ++tj) {
      int col = bn * 64 + wn + tj * 16 + lr;
      int buf = col >> 9, hd = col & 511;
      int h = hd >> 6, d = hd & 63;
#pragma unroll
      for (int r = 0; r < 4; ++r) {
        int row = bm * 64 + wm + ti * 16 + quad * 4 + r;
        int b = row >> 12, n = row & 4095;
        long addr = ((long)((b * 8 + h) * 4096 + n)) * 64 + d;
        float v = acc[ti][tj][r];
        if (buf == 0)      Qb[addr] = f2bf(v * 0.015625f);  // fold (dh^-0.5)^2 = 1/64
        else if (buf == 1) Kb[addr] = f2bf(v);
        else               Vb[addr] = f2bf(v);
      }
    }
}

// ---------------- output projection GEMM (+bias, fp32 out) ----------------
__global__ __launch_bounds__(256) void k_gemm_out(
    const unsigned short* __restrict__ A, const unsigned short* __restrict__ Bt,
    const float* __restrict__ bias, float* __restrict__ out) {
  __shared__ __align__(16) unsigned short As[64 * 40];
  __shared__ __align__(16) unsigned short Bs[64 * 40];
  const int t = threadIdx.x;
  const int bm = blockIdx.x, bn = blockIdx.y;
  const int w = t >> 6, l = t & 63, quad = l >> 4, lr = l & 15;
  const int wm = (w >> 1) * 32, wn = (w & 1) * 32;
  const f32x4 fz = {0.f, 0.f, 0.f, 0.f};
  f32x4 acc[2][2];
  acc[0][0] = fz; acc[0][1] = fz; acc[1][0] = fz; acc[1][1] = fz;
  const int srow = t >> 2, sc = (t & 3) * 8;
  const unsigned short* ag = A + (bm * 64 + srow) * 512 + sc;
  const unsigned short* bg = Bt + (bn * 64 + srow) * 512 + sc;
  for (int kk = 0; kk < 16; ++kk) {
    __syncthreads();
    *(s16x8*)&As[srow * 40 + sc] = *(const s16x8*)(ag + kk * 32);
    *(s16x8*)&Bs[srow * 40 + sc] = *(const s16x8*)(bg + kk * 32);
    __syncthreads();
    s16x8 af[2], bfr[2];
#pragma unroll
    for (int ti = 0; ti < 2; ++ti)
      af[ti] = *(const s16x8*)&As[(wm + ti * 16 + lr) * 40 + quad * 8];
#pragma unroll
    for (int tj = 0; tj < 2; ++tj)
      bfr[tj] = *(const s16x8*)&Bs[(wn + tj * 16 + lr) * 40 + quad * 8];
#pragma unroll
    for (int ti = 0; ti < 2; ++ti)
#pragma unroll
      for (int tj = 0; tj < 2; ++tj)
        acc[ti][tj] = MFMA16(af[ti], bfr[tj], acc[ti][tj]);
  }
#pragma unroll
  for (int ti = 0; ti < 2; ++ti)
#pragma unroll
    for (int tj = 0; tj < 2; ++tj) {
      int col = bn * 64 + wn + tj * 16 + lr;
      float bb = bias[col];
#pragma unroll
      for (int r = 0; r < 4; ++r) {
        int row = bm * 64 + wm + ti * 16 + quad * 4 + r;
        out[(long)row * 512 + col] = acc[ti][tj][r] + bb;
      }
    }
}

// ---------------- flash attention, causal ----------------
// grid (64 qtiles, 16 bh), 256 thr. Per wave: 16 q-rows. LDS (ushort elems):
//   Ks[64][72] @0, Vt[64][72] @4608 (dh-major), P/bounce per wave 16x72 @9216+w*1152
__global__ __launch_bounds__(256) void k_attn(
    const unsigned short* __restrict__ Qb, const unsigned short* __restrict__ Kb,
    const unsigned short* __restrict__ Vb, unsigned short* __restrict__ Ob) {
  __shared__ __align__(16) unsigned short lds[13824];
  const int t = threadIdx.x, w = t >> 6, l = t & 63, quad = l >> 4, lr = l & 15;
  const int qtile = blockIdx.x, bh = blockIdx.y;
  const int q0 = qtile * 64;
  const unsigned short* Qh = Qb + (long)bh * 262144;
  const unsigned short* Kh = Kb + (long)bh * 262144;
  const unsigned short* Vh = Vb + (long)bh * 262144;
  s16x8 qf[2];
  {
    int qr = q0 + w * 16 + lr;
    qf[0] = *(const s16x8*)(Qh + qr * 64 + quad * 8);
    qf[1] = *(const s16x8*)(Qh + qr * 64 + 32 + quad * 8);
  }
  const f32x4 fz = {0.f, 0.f, 0.f, 0.f};
  f32x4 o[4];
#pragma unroll
  for (int i = 0; i < 4; ++i) o[i] = fz;
  float m_r[4], l_r[4];
#pragma unroll
  for (int r = 0; r < 4; ++r) { m_r[r] = -3.0e38f; l_r[r] = 0.f; }
  const int PW = 9216 + w * 1152;

  for (int jt = 0; jt <= qtile; ++jt) {
    __syncthreads();  // previous iter's LDS reads done before restaging
#pragma unroll
    for (int i = 0; i < 2; ++i) {  // K tile: straight copy
      int c = t + i * 256;
      int row = c >> 3, d0 = (c & 7) * 8;
      *(s16x8*)&lds[row * 72 + d0] = *(const s16x8*)(Kh + (jt * 64 + row) * 64 + d0);
    }
#pragma unroll
    for (int i = 0; i < 2; ++i) {  // V tile: transpose to dh-major
      int c = t + i * 256;
      int n = c & 63, d0 = (c >> 6) * 8;
      s16x8 vv = *(const s16x8*)(Vh + (jt * 64 + n) * 64 + d0);
#pragma unroll
      for (int j = 0; j < 8; ++j)
        lds[4608 + (d0 + j) * 72 + n] = (unsigned short)vv[j];
    }
    __syncthreads();
    // S = Q K^T
    f32x4 s[4];
#pragma unroll
    for (int i = 0; i < 4; ++i) s[i] = fz;
#pragma unroll
    for (int c = 0; c < 2; ++c)
#pragma unroll
      for (int nt = 0; nt < 4; ++nt) {
        s16x8 kb = *(const s16x8*)&lds[(nt * 16 + lr) * 72 + c * 32 + quad * 8];
        s[nt] = MFMA16(qf[c], kb, s[nt]);
      }
    if (jt == qtile) {  // causal mask: only the diagonal tile needs it
#pragma unroll
      for (int nt = 0; nt < 4; ++nt)
#pragma unroll
        for (int r = 0; r < 4; ++r)
          if (nt * 16 + lr > w * 16 + quad * 4 + r) s[nt][r] = -1e30f;
    }
    // online softmax (row = quad*4+r, 16 lanes per row-group)
    float mnew[4], alpha[4];
#pragma unroll
    for (int r = 0; r < 4; ++r) {
      float lm = fmaxf(fmaxf(s[0][r], s[1][r]), fmaxf(s[2][r], s[3][r]));
      lm = fmaxf(lm, __shfl_xor(lm, 1));
      lm = fmaxf(lm, __shfl_xor(lm, 2));
      lm = fmaxf(lm, __shfl_xor(lm, 4));
      lm = fmaxf(lm, __shfl_xor(lm, 8));
      mnew[r] = fmaxf(m_r[r], lm);
      alpha[r] = __expf(m_r[r] - mnew[r]);
      m_r[r] = mnew[r];
    }
#pragma unroll
    for (int nt = 0; nt < 4; ++nt)
#pragma unroll
      for (int r = 0; r < 4; ++r) s[nt][r] = __expf(s[nt][r] - mnew[r]);
#pragma unroll
    for (int r = 0; r < 4; ++r) {
      float ts = (s[0][r] + s[1][r]) + (s[2][r] + s[3][r]);
      ts += __shfl_xor(ts, 1);
      ts += __shfl_xor(ts, 2);
      ts += __shfl_xor(ts, 4);
      ts += __shfl_xor(ts, 8);
      l_r[r] = l_r[r] * alpha[r] + ts;
    }
    // P (bf16) -> per-wave LDS region (C-layout -> A-layout round trip)
#pragma unroll
    for (int nt = 0; nt < 4; ++nt)
#pragma unroll
      for (int r = 0; r < 4; ++r)
        lds[PW + (quad * 4 + r) * 72 + nt * 16 + lr] = f2bf(s[nt][r]);
#pragma unroll
    for (int nt = 0; nt < 4; ++nt)
#pragma unroll
      for (int r = 0; r < 4; ++r) o[nt][r] *= alpha[r];
    __syncthreads();
    // O += P V
#pragma unroll
    for (int c = 0; c < 2; ++c) {
      s16x8 ap = *(const s16x8*)&lds[PW + lr * 72 + c * 32 + quad * 8];
#pragma unroll
      for (int nt = 0; nt < 4; ++nt) {
        s16x8 bv = *(const s16x8*)&lds[4608 + (nt * 16 + lr) * 72 + c * 32 + quad * 8];
        o[nt] = MFMA16(ap, bv, o[nt]);
      }
    }
  }
  // epilogue: normalize, bounce through LDS, vector store to [b,n,(h d)]
  float inv[4];
#pragma unroll
  for (int r = 0; r < 4; ++r) inv[r] = 1.0f / l_r[r];
#pragma unroll
  for (int nt = 0; nt < 4; ++nt)
#pragma unroll
    for (int r = 0; r < 4; ++r)
      lds[PW + (quad * 4 + r) * 72 + nt * 16 + lr] = f2bf(o[nt][r] * inv[r]);
  __syncthreads();
  const int b = bh >> 3, h = bh & 7;
  unsigned short* op = Ob + ((long)(b * 4096 + q0 + w * 16 + lr)) * 512 + h * 64 + quad * 16;
  *(s16x8*)op = *(const s16x8*)&lds[PW + lr * 72 + quad * 16];
  *(s16x8*)(op + 8) = *(const s16x8*)&lds[PW + lr * 72 + quad * 16 + 8];
}

extern "C" void kernel_launch(void* const* d_in, const int* in_sizes, int n_in,
                              void* d_out, int out_size, void* d_ws, size_t ws_size,
                              hipStream_t stream) {
  const float* x   = (const float*)d_in[0];
  const float* Wq  = (const float*)d_in[1];
  const float* Wkv = (const float*)d_in[2];
  const float* Wo  = (const float*)d_in[3];
  const float* bo  = (const float*)d_in[4];
  float* out = (float*)d_out;
  char* ws = (char*)d_ws;
  // workspace map (byte offsets, total 43 MB)
  unsigned short* xbf   = (unsigned short*)(ws + (0ull << 20));   // 8 MB
  unsigned short* wqkvt = (unsigned short*)(ws + (8ull << 20));   // 1.5 MB [1536][512]
  unsigned short* wot   = (unsigned short*)(ws + (10ull << 20));  // 0.5 MB [512][512]
  unsigned short* Qb    = (unsigned short*)(ws + (11ull << 20));  // 8 MB [16][4096][64]
  unsigned short* Kb    = (unsigned short*)(ws + (19ull << 20));  // 8 MB
  unsigned short* Vb    = (unsigned short*)(ws + (27ull << 20));  // 8 MB
  unsigned short* Ob    = (unsigned short*)(ws + (35ull << 20));  // 8 MB [8192][512]

  k_convert_x<<<4096, 256, 0, stream>>>(x, xbf);
  k_transpose_w<<<1024, 256, 0, stream>>>(Wq, wqkvt, 512);
  k_transpose_w<<<2048, 256, 0, stream>>>(Wkv, wqkvt + 512 * 512, 1024);
  k_transpose_w<<<1024, 256, 0, stream>>>(Wo, wot, 512);
  k_gemm_qkv<<<dim3(128, 24), 256, 0, stream>>>(xbf, wqkvt, Qb, Kb, Vb);
  k_attn<<<dim3(64, 16), 256, 0, stream>>>(Qb, Kb, Vb, Ob);
  k_gemm_out<<<dim3(128, 8), 256, 0, stream>>>(Ob, wot, bo, out);
}

// Round 2
// 249.511 us; speedup vs baseline: 1.4124x; 1.4124x over previous
//
#include <hip/hip_runtime.h>

typedef short s16x8 __attribute__((ext_vector_type(8)));
typedef float f32x4 __attribute__((ext_vector_type(4)));
typedef unsigned short u16;
typedef unsigned int u32;

#define MFMA16(a, b, c) __builtin_amdgcn_mfma_f32_16x16x32_bf16((a), (b), (c), 0, 0, 0)

__device__ __forceinline__ u16 f2bf(float f) {
  u32 u = __float_as_uint(f);
  u += 0x7fffu + ((u >> 16) & 1u);
  return (u16)(u >> 16);
}
// cheap round (half-up) for P in [0,1]; error <= 2^-9 relative
__device__ __forceinline__ u16 f2bf_fast(float f) {
  return (u16)((__float_as_uint(f) + 0x8000u) >> 16);
}
__device__ __forceinline__ float ex2(float x) {
  float r;
  asm("v_exp_f32 %0, %1" : "=v"(r) : "v"(x));
  return r;
}
// async global->LDS, 16B per lane; lds base must be wave-uniform
__device__ __forceinline__ void gll(const u16* g, u16* l) {
  __builtin_amdgcn_global_load_lds((const __attribute__((address_space(1))) u32*)g,
                                   (__attribute__((address_space(3))) u32*)l, 16, 0, 0);
}

// ---------------- fused prep: x->bf16, W^T->bf16 (LDS tile transpose) ----------------
__global__ __launch_bounds__(256) void k_prep(const float* __restrict__ x,
                                              const float* __restrict__ Wq,
                                              const float* __restrict__ Wkv,
                                              const float* __restrict__ Wo,
                                              u16* __restrict__ xb,
                                              u16* __restrict__ wqkvt,
                                              u16* __restrict__ wot) {
  const int bx = blockIdx.x, t = threadIdx.x;
  if (bx < 4096) {  // x convert, float4
    int i = bx * 256 + t;
    float4 v = ((const float4*)x)[i];
    ushort4 o;
    o.x = f2bf(v.x); o.y = f2bf(v.y); o.z = f2bf(v.z); o.w = f2bf(v.w);
    ((ushort4*)xb)[i] = o;
    return;
  }
  __shared__ u16 tl[64 * 66];
  const float* src; u16* dst; int N, kb, nb;
  if (bx < 4160)      { int tb = bx - 4096; src = Wq;  dst = wqkvt;          N = 512;  kb = tb >> 3; nb = tb & 7; }
  else if (bx < 4288) { int tb = bx - 4160; src = Wkv; dst = wqkvt + 262144; N = 1024; kb = tb >> 4; nb = tb & 15; }
  else                { int tb = bx - 4288; src = Wo;  dst = wot;            N = 512;  kb = tb >> 3; nb = tb & 7; }
#pragma unroll
  for (int it = 0; it < 4; ++it) {  // coalesced read of 64x64 f32 tile
    int idx = it * 256 + t;
    int kl = idx >> 4, nc = idx & 15;
    float4 v = *(const float4*)(src + (kb * 64 + kl) * N + nb * 64 + nc * 4);
    u16* p = &tl[kl * 66 + nc * 4];
    p[0] = f2bf(v.x); p[1] = f2bf(v.y); p[2] = f2bf(v.z); p[3] = f2bf(v.w);
  }
  __syncthreads();
#pragma unroll
  for (int it = 0; it < 2; ++it) {  // vectorized transposed write
    int idx = it * 256 + t;
    int nl = idx >> 3, kc = idx & 7;
    u16 tmp[8];
#pragma unroll
    for (int j = 0; j < 8; ++j) tmp[j] = tl[(kc * 8 + j) * 66 + nl];
    *(s16x8*)(dst + (nb * 64 + nl) * 512 + kb * 64 + kc * 8) = *(const s16x8*)tmp;
  }
}

// ---------------- QKV projection GEMM: 128x128 tile, BK=64, async swizzled staging ----------------
// C[8192,1536] = A[8192,512] * Bt[1536,512]^T ; scatter Q/K row-major [bh][n][64], V transposed [bh][d][n]
__global__ __launch_bounds__(256, 2) void k_gemm_qkv(
    const u16* __restrict__ A, const u16* __restrict__ Bt,
    u16* __restrict__ Qb, u16* __restrict__ Kb, u16* __restrict__ Vt) {
  __shared__ __align__(16) u16 As[8192], Bs[8192];
  const int t = threadIdx.x, w = t >> 6, l = t & 63, quad = l >> 4, lr = l & 15;
  const int bm = blockIdx.x, bn = blockIdx.y;
  const int wm = (w >> 1) * 64, wn = (w & 1) * 64;
  const f32x4 fz = {0.f, 0.f, 0.f, 0.f};
  f32x4 acc[4][4];
#pragma unroll
  for (int i = 0; i < 4; ++i)
#pragma unroll
    for (int j = 0; j < 4; ++j) acc[i][j] = fz;
  const u16* Ag = A + bm * 128 * 512;
  const u16* Bg = Bt + bn * 128 * 512;
  for (int kk = 0; kk < 8; ++kk) {
    __syncthreads();
#pragma unroll
    for (int i = 0; i < 4; ++i) {
      int ci = w * 256 + i * 64 + l;
      int row = ci >> 3, cb = ci & 7;
      int off = row * 512 + kk * 64 + ((cb ^ (row & 7)) << 3);
      gll(Ag + off, &As[w * 2048 + i * 512]);
      gll(Bg + off, &Bs[w * 2048 + i * 512]);
    }
    __syncthreads();
    s16x8 af[4][2], bf[4][2];
#pragma unroll
    for (int x2 = 0; x2 < 4; ++x2)
#pragma unroll
      for (int c = 0; c < 2; ++c) {
        int sw = ((c * 4 + quad) ^ (lr & 7)) << 3;
        af[x2][c] = *(const s16x8*)&As[(wm + x2 * 16 + lr) * 64 + sw];
        bf[x2][c] = *(const s16x8*)&Bs[(wn + x2 * 16 + lr) * 64 + sw];
      }
#pragma unroll
    for (int c = 0; c < 2; ++c)
#pragma unroll
      for (int ti = 0; ti < 4; ++ti)
#pragma unroll
        for (int tj = 0; tj < 4; ++tj)
          acc[ti][tj] = MFMA16(af[ti][c], bf[tj][c], acc[ti][tj]);
  }
  const int buf = (bn * 128) >> 9;  // uniform: 0=Q,1=K,2=V
  const float QS = 0.0225421107f;   // log2(e)/64 : both dh^-0.5 scalings + exp2 domain
#pragma unroll
  for (int ti = 0; ti < 4; ++ti)
#pragma unroll
    for (int tj = 0; tj < 4; ++tj) {
      int col = bn * 128 + wn + tj * 16 + lr;
      int hd = col & 511, h = hd >> 6, d = hd & 63;
      int row0 = bm * 128 + wm + ti * 16 + quad * 4;
      int b = row0 >> 12, n0 = row0 & 4095;
      long base = (long)(b * 8 + h) * 262144;
      if (buf == 0) {
#pragma unroll
        for (int r = 0; r < 4; ++r) Qb[base + (long)(n0 + r) * 64 + d] = f2bf(acc[ti][tj][r] * QS);
      } else if (buf == 1) {
#pragma unroll
        for (int r = 0; r < 4; ++r) Kb[base + (long)(n0 + r) * 64 + d] = f2bf(acc[ti][tj][r]);
      } else {
        ushort4 pk;
        pk.x = f2bf(acc[ti][tj][0]); pk.y = f2bf(acc[ti][tj][1]);
        pk.z = f2bf(acc[ti][tj][2]); pk.w = f2bf(acc[ti][tj][3]);
        *(ushort4*)&Vt[base + (long)d * 4096 + n0] = pk;  // transposed: [bh][d][n]
      }
    }
}

// ---------------- output projection GEMM (+bias, fp32 out): same structure ----------------
__global__ __launch_bounds__(256, 2) void k_gemm_out(
    const u16* __restrict__ A, const u16* __restrict__ Bt,
    const float* __restrict__ bias, float* __restrict__ out) {
  __shared__ __align__(16) u16 As[8192], Bs[8192];
  const int t = threadIdx.x, w = t >> 6, l = t & 63, quad = l >> 4, lr = l & 15;
  const int bm = blockIdx.x, bn = blockIdx.y;
  const int wm = (w >> 1) * 64, wn = (w & 1) * 64;
  const f32x4 fz = {0.f, 0.f, 0.f, 0.f};
  f32x4 acc[4][4];
#pragma unroll
  for (int i = 0; i < 4; ++i)
#pragma unroll
    for (int j = 0; j < 4; ++j) acc[i][j] = fz;
  const u16* Ag = A + bm * 128 * 512;
  const u16* Bg = Bt + bn * 128 * 512;
  for (int kk = 0; kk < 8; ++kk) {
    __syncthreads();
#pragma unroll
    for (int i = 0; i < 4; ++i) {
      int ci = w * 256 + i * 64 + l;
      int row = ci >> 3, cb = ci & 7;
      int off = row * 512 + kk * 64 + ((cb ^ (row & 7)) << 3);
      gll(Ag + off, &As[w * 2048 + i * 512]);
      gll(Bg + off, &Bs[w * 2048 + i * 512]);
    }
    __syncthreads();
    s16x8 af[4][2], bf[4][2];
#pragma unroll
    for (int x2 = 0; x2 < 4; ++x2)
#pragma unroll
      for (int c = 0; c < 2; ++c) {
        int sw = ((c * 4 + quad) ^ (lr & 7)) << 3;
        af[x2][c] = *(const s16x8*)&As[(wm + x2 * 16 + lr) * 64 + sw];
        bf[x2][c] = *(const s16x8*)&Bs[(wn + x2 * 16 + lr) * 64 + sw];
      }
#pragma unroll
    for (int c = 0; c < 2; ++c)
#pragma unroll
      for (int ti = 0; ti < 4; ++ti)
#pragma unroll
        for (int tj = 0; tj < 4; ++tj)
          acc[ti][tj] = MFMA16(af[ti][c], bf[tj][c], acc[ti][tj]);
  }
#pragma unroll
  for (int ti = 0; ti < 4; ++ti)
#pragma unroll
    for (int tj = 0; tj < 4; ++tj) {
      int col = bn * 128 + wn + tj * 16 + lr;
      float bb = bias[col];
#pragma unroll
      for (int r = 0; r < 4; ++r) {
        int row = bm * 128 + wm + ti * 16 + quad * 4 + r;
        out[(long)row * 512 + col] = acc[ti][tj][r] + bb;
      }
    }
}

// ---------------- flash attention, causal. 128 thr (2 waves x 32 q-rows), LPT-ordered grid ----------------
// LDS (u16 elems): Ks[64][64] swizzled @0, Vts[64][64] swizzled @4096, P per wave 32x72 @8192+w*2304
__global__ __launch_bounds__(128, 2) void k_attn(
    const u16* __restrict__ Qb, const u16* __restrict__ Kb,
    const u16* __restrict__ Vt, u16* __restrict__ Ob) {
  __shared__ __align__(16) u16 lds[12800];
  const int t = threadIdx.x, w = t >> 6, l = t & 63, quad = l >> 4, lr = l & 15;
  const int bid = blockIdx.x;
  const int qb = 63 - (bid >> 4), bh = bid & 15;  // heaviest q-blocks launch first
  const u16* Qh = Qb + (long)bh * 262144;
  const u16* Kh = Kb + (long)bh * 262144;
  const u16* Vh = Vt + (long)bh * 262144;  // [64][4096]
  const int q0 = qb * 64, rw0 = q0 + w * 32;
  s16x8 qf[2][2];
#pragma unroll
  for (int mt = 0; mt < 2; ++mt)
#pragma unroll
    for (int c = 0; c < 2; ++c)
      qf[mt][c] = *(const s16x8*)(Qh + (rw0 + mt * 16 + lr) * 64 + c * 32 + quad * 8);
  const f32x4 fz = {0.f, 0.f, 0.f, 0.f};
  f32x4 o[2][4];
#pragma unroll
  for (int mt = 0; mt < 2; ++mt)
#pragma unroll
    for (int nt = 0; nt < 4; ++nt) o[mt][nt] = fz;
  float m_r[2][4], l_r[2][4];
#pragma unroll
  for (int mt = 0; mt < 2; ++mt)
#pragma unroll
    for (int r = 0; r < 4; ++r) { m_r[mt][r] = -3.0e38f; l_r[mt][r] = 0.f; }
  u16* P = &lds[8192 + w * 2304];

  for (int jt = 0; jt <= qb; ++jt) {
    __syncthreads();  // prev iter's K/V reads done before restage
    const u16* Ksrc = Kh + jt * 4096;
    const u16* Vsrc = Vh + jt * 64;
#pragma unroll
    for (int i = 0; i < 4; ++i) {
      int ci = (w * 4 + i) * 64 + l;
      int row = ci >> 3, cb = ci & 7;
      int sw = (cb ^ (row & 7)) << 3;
      gll(Ksrc + row * 64 + sw, &lds[(w * 4 + i) * 512]);
      gll(Vsrc + row * 4096 + sw, &lds[4096 + (w * 4 + i) * 512]);
    }
    __syncthreads();  // drains vmcnt for global_load_lds
    // S = Q K^T (log2 domain, scale folded into Q)
    f32x4 s[2][4];
#pragma unroll
    for (int mt = 0; mt < 2; ++mt)
#pragma unroll
      for (int nt = 0; nt < 4; ++nt) s[mt][nt] = fz;
#pragma unroll
    for (int c = 0; c < 2; ++c) {
      s16x8 kbf[4];
#pragma unroll
      for (int nt = 0; nt < 4; ++nt)
        kbf[nt] = *(const s16x8*)&lds[(nt * 16 + lr) * 64 + (((c * 4 + quad) ^ (lr & 7)) << 3)];
#pragma unroll
      for (int mt = 0; mt < 2; ++mt)
#pragma unroll
        for (int nt = 0; nt < 4; ++nt)
          s[mt][nt] = MFMA16(qf[mt][c], kbf[nt], s[mt][nt]);
    }
    const bool dg = (jt == qb);
#pragma unroll
    for (int mt = 0; mt < 2; ++mt) {
      if (dg) {  // causal mask, diagonal tile only
        int rloc = rw0 - jt * 64 + mt * 16 + quad * 4;
#pragma unroll
        for (int nt = 0; nt < 4; ++nt)
#pragma unroll
          for (int r = 0; r < 4; ++r)
            if (nt * 16 + lr > rloc + r) s[mt][nt][r] = -1e30f;
      }
      float al[4];
#pragma unroll
      for (int r = 0; r < 4; ++r) {
        float lm = fmaxf(fmaxf(s[mt][0][r], s[mt][1][r]), fmaxf(s[mt][2][r], s[mt][3][r]));
        lm = fmaxf(lm, __shfl_xor(lm, 1));
        lm = fmaxf(lm, __shfl_xor(lm, 2));
        lm = fmaxf(lm, __shfl_xor(lm, 4));
        lm = fmaxf(lm, __shfl_xor(lm, 8));
        float mn = fmaxf(m_r[mt][r], lm);
        al[r] = ex2(m_r[mt][r] - mn);
        m_r[mt][r] = mn;
      }
#pragma unroll
      for (int nt = 0; nt < 4; ++nt)
#pragma unroll
        for (int r = 0; r < 4; ++r) s[mt][nt][r] = ex2(s[mt][nt][r] - m_r[mt][r]);
#pragma unroll
      for (int r = 0; r < 4; ++r) {
        float ts = (s[mt][0][r] + s[mt][1][r]) + (s[mt][2][r] + s[mt][3][r]);
        ts += __shfl_xor(ts, 1);
        ts += __shfl_xor(ts, 2);
        ts += __shfl_xor(ts, 4);
        ts += __shfl_xor(ts, 8);
        l_r[mt][r] = l_r[mt][r] * al[r] + ts;
      }
#pragma unroll
      for (int nt = 0; nt < 4; ++nt)
#pragma unroll
        for (int r = 0; r < 4; ++r)
          P[(mt * 16 + quad * 4 + r) * 72 + nt * 16 + lr] = f2bf_fast(s[mt][nt][r]);
#pragma unroll
      for (int nt = 0; nt < 4; ++nt)
#pragma unroll
        for (int r = 0; r < 4; ++r) o[mt][nt][r] *= al[r];
    }
    // O += P V   (P region is per-wave: no barrier, lgkmcnt handles RAW)
#pragma unroll
    for (int c = 0; c < 2; ++c) {
      s16x8 ap[2], bv[4];
#pragma unroll
      for (int mt = 0; mt < 2; ++mt)
        ap[mt] = *(const s16x8*)&P[(mt * 16 + lr) * 72 + c * 32 + quad * 8];
#pragma unroll
      for (int nt = 0; nt < 4; ++nt)
        bv[nt] = *(const s16x8*)&lds[4096 + (nt * 16 + lr) * 64 + (((c * 4 + quad) ^ (lr & 7)) << 3)];
#pragma unroll
      for (int mt = 0; mt < 2; ++mt)
#pragma unroll
        for (int nt = 0; nt < 4; ++nt)
          o[mt][nt] = MFMA16(ap[mt], bv[nt], o[mt][nt]);
    }
  }
  // epilogue: normalize, bounce through per-wave LDS, vector store
#pragma unroll
  for (int mt = 0; mt < 2; ++mt) {
    float inv[4];
#pragma unroll
    for (int r = 0; r < 4; ++r) inv[r] = 1.0f / l_r[mt][r];
#pragma unroll
    for (int nt = 0; nt < 4; ++nt)
#pragma unroll
      for (int r = 0; r < 4; ++r)
        P[(mt * 16 + quad * 4 + r) * 72 + nt * 16 + lr] = f2bf(o[mt][nt][r] * inv[r]);
  }
  const int b = bh >> 3, h = bh & 7;
  const int row2 = l >> 1, half = l & 1;
  long gbase = (long)(b * 4096 + rw0 + row2) * 512 + h * 64 + half * 32;
  const u16* ps = &P[row2 * 72 + half * 32];
#pragma unroll
  for (int k = 0; k < 4; ++k)
    *(s16x8*)(Ob + gbase + k * 8) = *(const s16x8*)(ps + k * 8);
}

extern "C" void kernel_launch(void* const* d_in, const int* in_sizes, int n_in,
                              void* d_out, int out_size, void* d_ws, size_t ws_size,
                              hipStream_t stream) {
  const float* x   = (const float*)d_in[0];
  const float* Wq  = (const float*)d_in[1];
  const float* Wkv = (const float*)d_in[2];
  const float* Wo  = (const float*)d_in[3];
  const float* bo  = (const float*)d_in[4];
  float* out = (float*)d_out;
  char* ws = (char*)d_ws;
  u16* xbf   = (u16*)(ws + (0ull << 20));   // 8 MB   [8192][512]
  u16* wqkvt = (u16*)(ws + (8ull << 20));   // 1.5 MB [1536][512]
  u16* wot   = (u16*)(ws + (10ull << 20));  // 0.5 MB [512][512]
  u16* Qb    = (u16*)(ws + (11ull << 20));  // 8 MB   [16][4096][64]
  u16* Kb    = (u16*)(ws + (19ull << 20));  // 8 MB   [16][4096][64]
  u16* Vtb   = (u16*)(ws + (27ull << 20));  // 8 MB   [16][64][4096] (transposed)
  u16* Ob    = (u16*)(ws + (35ull << 20));  // 8 MB   [8192][512]

  k_prep<<<4352, 256, 0, stream>>>(x, Wq, Wkv, Wo, xbf, wqkvt, wot);
  k_gemm_qkv<<<dim3(64, 12), 256, 0, stream>>>(xbf, wqkvt, Qb, Kb, Vtb);
  k_attn<<<1024, 128, 0, stream>>>(Qb, Kb, Vtb, Ob);
  k_gemm_out<<<dim3(64, 4), 256, 0, stream>>>(Ob, wot, bo, out);
}